// Round 2
// baseline (1822.386 us; speedup 1.0000x reference)
//
#include <hip/hip_runtime.h>

#define AS1 __attribute__((address_space(1)))
#define AS3 __attribute__((address_space(3)))

typedef __attribute__((ext_vector_type(4))) float f32x4;
typedef __attribute__((ext_vector_type(8))) short s16x8;
typedef __attribute__((ext_vector_type(4))) short s16x4;

static constexpr int BB = 256, SS = 128, OBSN = 256, HH = 1024, AN = 18;
static constexpr int MM = BB * SS;   // 32768
static constexpr int G4 = 4 * HH;    // 4096

static constexpr int LP_OFF  = MM * AN;            // 589824
static constexpr int ENT_OFF = LP_OFF + MM;        // 622592
static constexpr int VAL_OFF = ENT_OFF + MM;       // 655360

__device__ __forceinline__ short f2bf(float f) {
  unsigned u = __builtin_bit_cast(unsigned, f);
  u += 0x7FFFu + ((u >> 16) & 1u);
  return (short)(u >> 16);
}
__device__ __forceinline__ float bf2f(short s) {
  unsigned u = ((unsigned)(unsigned short)s) << 16;
  return __builtin_bit_cast(float, u);
}
__device__ __forceinline__ void gl_lds16(const void* g, void* l) {
  __builtin_amdgcn_global_load_lds((const AS1 void*)g, (AS3 void*)l, 16, 0, 0);
}
__device__ __forceinline__ float sigf(float x) {
  x = fminf(fmaxf(x, -30.f), 30.f);
  return 1.f / (1.f + __expf(-x));
}
__device__ __forceinline__ float tanhfast(float x) {
  x = fminf(fmaxf(x, -15.f), 15.f);
  float e = __expf(2.f * x);
  return (e - 1.f) / (e + 1.f);
}
__device__ __forceinline__ void cast4(const float* __restrict__ s,
                                      short* __restrict__ d, int i) {
  f32x4 v = ((const f32x4*)s)[i];
  s16x4 o;
  o[0] = f2bf(v[0]); o[1] = f2bf(v[1]); o[2] = f2bf(v[2]); o[3] = f2bf(v[3]);
  ((s16x4*)d)[i] = o;
}

// ---------------- prep: casts + bias fold + state init --------------------
__global__ __launch_bounds__(256) void prep(
    const float* __restrict__ obs, const float* __restrict__ Wb,
    const float* __restrict__ Wih, const float* __restrict__ Whh,
    const float* __restrict__ Wl, const float* __restrict__ Wv,
    const float* __restrict__ bih, const float* __restrict__ bhh,
    const float* __restrict__ hx, const float* __restrict__ cx,
    short* __restrict__ obsb, short* __restrict__ wbo, short* __restrict__ wiho,
    short* __restrict__ whho, short* __restrict__ wlo, short* __restrict__ wvo,
    float* __restrict__ bsum, short* __restrict__ h0o, float* __restrict__ co) {
  int i = blockIdx.x * 256 + threadIdx.x;   // float4 units
  if (i < 2097152) { cast4(obs, obsb, i); return; }
  i -= 2097152;
  if (i < 65536) { cast4(Wb, wbo, i); return; }
  i -= 65536;
  if (i < 1048576) { cast4(Wih, wiho, i); return; }
  i -= 1048576;
  if (i < 1048576) { cast4(Whh, whho, i); return; }
  i -= 1048576;
  if (i < 4608) { cast4(Wl, wlo, i); return; }
  i -= 4608;
  if (i < 256) { cast4(Wv, wvo, i); return; }
  i -= 256;
  if (i < 1024) {
    f32x4 a = ((const f32x4*)bih)[i];
    f32x4 b = ((const f32x4*)bhh)[i];
    ((f32x4*)bsum)[i] = a + b;
    return;
  }
  i -= 1024;
  // i < 65536: hx -> h0 bf16, cx -> c f32
  cast4(hx, h0o, i);
  ((f32x4*)co)[i] = ((const f32x4*)cx)[i];
}

// ---------------- bf16 B^T GEMM, 128x128 tile, BK=32 (m97 structure) ------
// C[m][n] = act( sum_k A[m][k]*Bw[n][k] + bias[n] ), C stored bf16 (row-major
// logical). REMAP==1: logical row m (= sl*256 + b) is read from A physical
// row b*SS + t0 + sl (obs layout [b][s][*]).
template <int N, int K, bool RELU, int REMAP>
__global__ __launch_bounds__(256, 2) void gemm_bt(
    const short* __restrict__ A, const short* __restrict__ Bw,
    const float* __restrict__ bias, short* __restrict__ C, int t0) {
  __shared__ short lA[128 * 32];
  __shared__ short lB[128 * 32];
  const int tid = threadIdx.x;
  const int lane = tid & 63, wave = tid >> 6;
  const int nTN = N / 128;
  const int tm = blockIdx.x / nTN, tn = blockIdx.x % nTN;

  const int r0 = tid >> 2;          // 0..63 staging row
  const int kc = (tid & 3) * 8;     // element offset in row

  const int m0 = tm * 128 + r0;
  const int m1 = m0 + 64;
  size_t pr0, pr1;
  if constexpr (REMAP == 1) {
    pr0 = (size_t)((m0 & (BB - 1)) * SS + t0 + (m0 >> 8));
    pr1 = (size_t)((m1 & (BB - 1)) * SS + t0 + (m1 >> 8));
  } else {
    pr0 = (size_t)m0; pr1 = (size_t)m1;
  }
  const short* a0 = A + pr0 * K + kc;
  const short* a1 = A + pr1 * K + kc;
  const short* b0 = Bw + (size_t)(tn * 128 + r0) * K + kc;
  const short* b1 = Bw + (size_t)(tn * 128 + r0 + 64) * K + kc;

  f32x4 acc[4][4];
#pragma unroll
  for (int i = 0; i < 4; ++i)
#pragma unroll
    for (int j = 0; j < 4; ++j) acc[i][j] = {0.f, 0.f, 0.f, 0.f};

  const int wr = (wave >> 1) * 64;
  const int wc = (wave & 1) * 64;
  const int fr = lane & 15;
  const int fk = (lane >> 4) * 8;

  for (int k0 = 0; k0 < K; k0 += 32) {
    __syncthreads();
    gl_lds16(a0 + k0, &lA[tid * 8]);
    gl_lds16(a1 + k0, &lA[2048 + tid * 8]);
    gl_lds16(b0 + k0, &lB[tid * 8]);
    gl_lds16(b1 + k0, &lB[2048 + tid * 8]);
    __syncthreads();
    s16x8 af[4], bfr[4];
#pragma unroll
    for (int i = 0; i < 4; ++i)
      af[i] = *(const s16x8*)&lA[(wr + i * 16 + fr) * 32 + fk];
#pragma unroll
    for (int j = 0; j < 4; ++j)
      bfr[j] = *(const s16x8*)&lB[(wc + j * 16 + fr) * 32 + fk];
#pragma unroll
    for (int i = 0; i < 4; ++i)
#pragma unroll
      for (int j = 0; j < 4; ++j)
        acc[i][j] = __builtin_amdgcn_mfma_f32_16x16x32_bf16(af[i], bfr[j], acc[i][j], 0, 0, 0);
  }

  const int orow = (lane >> 4) * 4;
#pragma unroll
  for (int i = 0; i < 4; ++i) {
#pragma unroll
    for (int j = 0; j < 4; ++j) {
      const int colg = tn * 128 + wc + j * 16 + fr;
      const float bv = bias[colg];
#pragma unroll
      for (int r = 0; r < 4; ++r) {
        const int rowg = tm * 128 + wr + i * 16 + orow + r;
        float v = acc[i][j][r] + bv;
        if (RELU) v = v > 0.f ? v : 0.f;
        C[(size_t)rowg * N + colg] = f2bf(v);
      }
    }
  }
}

// ---------------- LSTM step: 256 WGs (8 b-tiles x 32 h-tiles) -------------
// wave g computes gate g's 32x32 tile; BK=128 with XOR-swizzled staging
// (linear LDS dest + inverse-swizzled global source + swizzled ds_read).
__global__ __launch_bounds__(256, 2) void lstm_step(
    const short* __restrict__ h_in, short* __restrict__ h_out,
    float* __restrict__ cst, const short* __restrict__ Whh,
    const short* __restrict__ xg_s,   // xg_chunk + sl*B*4H  ([b][4H] bf16)
    short* __restrict__ hs_s) {       // hs_chunk + sl*B*H  ([b][H] bf16)
  __shared__ char smem[40960];        // staging 40KB; epilogue lG 16KB overlays
  float* lG = (float*)smem;
  short* smS = (short*)smem;

  const int tid = threadIdx.x, lane = tid & 63, wave = tid >> 6;
  const int bt = blockIdx.x >> 5, ht = blockIdx.x & 31;
  const int b0 = bt * 32, h0 = ht * 32;

  const int lq = lane >> 4;   // 0..3
  const int lc = lane & 15;   // 16B chunk idx within 256B row

  // W staging sources: gate=wave, rows h0..h0+31 of that gate; source chunk
  // pre-XOR'd by (row&7) so a linear LDS write yields the swizzled layout.
  const short* wsrc[8];
  {
    const size_t rowbase = (size_t)(wave * HH + h0 + lq) * HH;
#pragma unroll
    for (int q = 0; q < 8; ++q)
      wsrc[q] = Whh + rowbase + (size_t)q * 4 * HH +
                (size_t)((lc ^ (((q & 1) << 2) | lq)) * 8);
  }
  // h staging sources (waves 0,1 only): rows b0..b0+31
  const short* hsrc[4];
  {
    const size_t rowbase = (size_t)(b0 + (wave & 1) * 16 + lq) * HH;
#pragma unroll
    for (int q = 0; q < 4; ++q)
      hsrc[q] = h_in + rowbase + (size_t)q * 4 * HH +
                (size_t)((lc ^ (((q & 1) << 2) | lq)) * 8);
  }

  const int fr = lane & 15;
  f32x4 acc[2][2];
#pragma unroll
  for (int i = 0; i < 2; ++i)
#pragma unroll
    for (int j = 0; j < 2; ++j) acc[i][j] = {0.f, 0.f, 0.f, 0.f};

  for (int it = 0; it < 8; ++it) {
    const int k0 = it * 128;
    __syncthreads();
#pragma unroll
    for (int q = 0; q < 8; ++q)
      gl_lds16(wsrc[q] + k0, &smS[4096 + wave * 4096 + q * 512 + lane * 8]);
    if (wave < 2) {
#pragma unroll
      for (int q = 0; q < 4; ++q)
        gl_lds16(hsrc[q] + k0, &smS[wave * 2048 + q * 512 + lane * 8]);
    }
    __syncthreads();
#pragma unroll
    for (int kk = 0; kk < 4; ++kk) {
      const int sw = ((kk * 4 + lq) ^ (fr & 7)) * 8;  // swizzled chunk offset
      s16x8 ha[2], wb[2];
#pragma unroll
      for (int i = 0; i < 2; ++i)
        ha[i] = *(const s16x8*)&smS[(i * 16 + fr) * 128 + sw];
#pragma unroll
      for (int j = 0; j < 2; ++j)
        wb[j] = *(const s16x8*)&smS[4096 + wave * 4096 + (j * 16 + fr) * 128 + sw];
#pragma unroll
      for (int i = 0; i < 2; ++i)
#pragma unroll
        for (int j = 0; j < 2; ++j)
          acc[i][j] = __builtin_amdgcn_mfma_f32_16x16x32_bf16(ha[i], wb[j], acc[i][j], 0, 0, 0);
    }
  }
  __syncthreads();
  // gates -> LDS (f32): gate=wave tile [32 rows batch][32 cols hidden]
#pragma unroll
  for (int i = 0; i < 2; ++i)
#pragma unroll
    for (int j = 0; j < 2; ++j)
#pragma unroll
      for (int r = 0; r < 4; ++r) {
        const int row = i * 16 + lq * 4 + r;
        const int col = j * 16 + fr;
        lG[wave * 1024 + row * 32 + col] = acc[i][j][r];
      }
  __syncthreads();

  // elementwise cell update: 256 threads x 4 cols
  const int er = tid >> 3, cb = (tid & 7) * 4;
  const int b = b0 + er;
  const size_t xgb = (size_t)b * G4 + h0 + cb;
  const s16x4 xi = *(const s16x4*)&xg_s[xgb];
  const s16x4 xf = *(const s16x4*)&xg_s[xgb + HH];
  const s16x4 xc = *(const s16x4*)&xg_s[xgb + 2 * HH];
  const s16x4 xo = *(const s16x4*)&xg_s[xgb + 3 * HH];
  const size_t cib = (size_t)b * HH + h0 + cb;
  f32x4 cv = *(const f32x4*)&cst[cib];
  s16x4 hb;
#pragma unroll
  for (int q = 0; q < 4; ++q) {
    const int col = cb + q;
    const float gi = lG[0 * 1024 + er * 32 + col] + bf2f(xi[q]);
    const float gf = lG[1 * 1024 + er * 32 + col] + bf2f(xf[q]);
    const float gc = lG[2 * 1024 + er * 32 + col] + bf2f(xc[q]);
    const float go = lG[3 * 1024 + er * 32 + col] + bf2f(xo[q]);
    const float iv = sigf(gi), fv = sigf(gf), gv = tanhfast(gc), ov = sigf(go);
    const float cn = fv * cv[q] + iv * gv;
    cv[q] = cn;
    hb[q] = f2bf(ov * tanhfast(cn));
  }
  *(f32x4*)&cst[cib] = cv;
  *(s16x4*)&h_out[cib] = hb;
  *(s16x4*)&hs_s[cib] = hb;
}

// ---------------- heads: wave per row ------------------------------------
// hs rows r = sl*256 + b (chunk-local); global m = b*SS + t0 + sl.
__global__ __launch_bounds__(256) void heads_k(
    const short* __restrict__ hs, const short* __restrict__ Wl,
    const float* __restrict__ bl, const short* __restrict__ Wv,
    const float* __restrict__ bv, const int* __restrict__ acts,
    float* __restrict__ out, int t0) {
  const int tid = threadIdx.x, lane = tid & 63, wave = tid >> 6;
  const int r = blockIdx.x * 4 + wave;
  const int sl = r >> 8, b = r & 255;
  const int mg = b * SS + t0 + sl;
  const short* hrow = hs + (size_t)r * HH + lane * 16;
  const s16x8 hv0 = *(const s16x8*)hrow;
  const s16x8 hv1 = *(const s16x8*)(hrow + 8);
  float xv[16];
#pragma unroll
  for (int e = 0; e < 8; ++e) { xv[e] = bf2f(hv0[e]); xv[8 + e] = bf2f(hv1[e]); }

  float lg[19];
#pragma unroll
  for (int j = 0; j < 19; ++j) {
    const short* wp = (j < 18 ? Wl + (size_t)j * HH : Wv) + lane * 16;
    const s16x8 w0 = *(const s16x8*)wp;
    const s16x8 w1 = *(const s16x8*)(wp + 8);
    float s = 0.f;
#pragma unroll
    for (int e = 0; e < 8; ++e) s += xv[e] * bf2f(w0[e]) + xv[8 + e] * bf2f(w1[e]);
#pragma unroll
    for (int d = 32; d >= 1; d >>= 1) s += __shfl_xor(s, d, 64);
    lg[j] = s + (j < 18 ? bl[j] : bv[0]);
  }
  float mx = lg[0];
#pragma unroll
  for (int j = 1; j < 18; ++j) mx = fmaxf(mx, lg[j]);
  float se = 0.f;
#pragma unroll
  for (int j = 0; j < 18; ++j) se += __expf(lg[j] - mx);
  const float lse = __logf(se);
  if (lane == 0) {
    const int act = acts[mg];
    float ent = 0.f, sel = 0.f;
#pragma unroll
    for (int j = 0; j < 18; ++j) {
      const float lp = lg[j] - mx - lse;
      out[(size_t)mg * 18 + j] = lp;
      ent -= __expf(lp) * lp;
      if (j == act) sel = lp;
    }
    out[LP_OFF + mg] = sel;
    out[ENT_OFF + mg] = ent;
    out[VAL_OFF + mg] = lg[18];
  }
}

// ---------------- launch ---------------------------------------------------
extern "C" void kernel_launch(void* const* d_in, const int* in_sizes, int n_in,
                              void* d_out, int out_size, void* d_ws, size_t ws_size,
                              hipStream_t stream) {
  const float* obs    = (const float*)d_in[0];
  const float* hx     = (const float*)d_in[1];
  const float* cx     = (const float*)d_in[2];
  const int*   acts   = (const int*)d_in[3];
  const float* W_body = (const float*)d_in[4];
  const float* b_body = (const float*)d_in[5];
  const float* W_ih   = (const float*)d_in[6];
  const float* b_ih   = (const float*)d_in[7];
  const float* W_hh   = (const float*)d_in[8];
  const float* b_hh   = (const float*)d_in[9];
  const float* W_v    = (const float*)d_in[10];
  const float* b_v    = (const float*)d_in[11];
  const float* W_l    = (const float*)d_in[12];
  const float* b_l    = (const float*)d_in[13];
  float* out = (float*)d_out;
  (void)in_sizes; (void)n_in; (void)out_size;

  // Pick the largest time-chunk whose workspace footprint fits ws_size.
  const size_t FIXED = 36231168ull;      // weights + obsb + h/c state (bytes)
  const size_t PER_C = 3145728ull;       // x_chunk + xg_chunk + hs_chunk per step
  int chunk = 16;
  while (chunk > 1 && FIXED + (size_t)chunk * PER_C > ws_size) chunk >>= 1;

  char* ws = (char*)d_ws;
  size_t off = 0;
  auto give = [&](size_t bytes) -> char* {
    char* p = ws + off;
    off += (bytes + 255) & ~(size_t)255;
    return p;
  };
  short* wb   = (short*)give((size_t)HH * OBSN * 2);
  short* wih  = (short*)give((size_t)G4 * HH * 2);
  short* whh  = (short*)give((size_t)G4 * HH * 2);
  short* wl   = (short*)give((size_t)AN * HH * 2);
  short* wv   = (short*)give((size_t)HH * 2);
  float* bsum = (float*)give((size_t)G4 * 4);
  short* obsb = (short*)give((size_t)MM * OBSN * 2);
  short* h0b  = (short*)give((size_t)BB * HH * 2);
  short* h1b  = (short*)give((size_t)BB * HH * 2);
  float* cbuf = (float*)give((size_t)BB * HH * 4);
  short* xc   = (short*)give((size_t)chunk * BB * HH * 2);
  short* xgc  = (short*)give((size_t)chunk * BB * G4 * 2);
  short* hsc  = (short*)give((size_t)chunk * BB * HH * 2);

  prep<<<16919, 256, 0, stream>>>(obs, W_body, W_ih, W_hh, W_l, W_v, b_ih, b_hh,
                                  hx, cx, obsb, wb, wih, whh, wl, wv, bsum, h0b, cbuf);

  short* ha = h0b;
  short* hb = h1b;
  const int Mc = chunk * BB;
  for (int t0 = 0; t0 < SS; t0 += chunk) {
    gemm_bt<HH, OBSN, true, 1>
        <<<(Mc / 128) * (HH / 128), 256, 0, stream>>>(obsb, wb, b_body, xc, t0);
    gemm_bt<G4, HH, false, 0>
        <<<(Mc / 128) * (G4 / 128), 256, 0, stream>>>(xc, wih, bsum, xgc, 0);
    for (int sl = 0; sl < chunk; ++sl) {
      lstm_step<<<256, 256, 0, stream>>>(ha, hb, cbuf, whh,
                                         xgc + (size_t)sl * BB * G4,
                                         hsc + (size_t)sl * BB * HH);
      short* t = ha; ha = hb; hb = t;
    }
    heads_k<<<Mc / 4, 256, 0, stream>>>(hsc, wl, b_l, wv, b_v, acts, out, t0);
  }
}